// Round 3
// baseline (176.713 us; speedup 1.0000x reference)
//
#include <hip/hip_runtime.h>

#define NPTS 65536
#define WW 1024
#define HWCELLS 65536
#define EPSF 1e-5f
#define QPTS 32

typedef __attribute__((ext_vector_type(8))) short short8;
typedef __attribute__((ext_vector_type(4))) float f32x4;

// fast exact-gelu: Abramowitz-Stegun 7.1.25 erf approx (|err| <= 2.5e-5)
__device__ __forceinline__ float gelu_f(float x) {
    float z  = fabsf(x) * 0.70710678118654752f;
    float t  = __builtin_amdgcn_rcpf(fmaf(0.47047f, z, 1.0f));
    float p  = fmaf(fmaf(0.7478556f, t, -0.0958798f), t, 0.3480242f) * t;
    float e  = __builtin_amdgcn_exp2f(-1.4426950408889634f * z * z);
    float er = fmaf(-p, e, 1.0f);          // erf(|x|/sqrt2)
    float s  = copysignf(er, x);
    float hx = 0.5f * x;
    return fmaf(hx, s, hx);
}
__device__ __forceinline__ unsigned f2bf_rne(float x) {
    unsigned u = __float_as_uint(x);
    return (u + 0x7fffu + ((u >> 16) & 1u)) >> 16;
}
__device__ __forceinline__ unsigned pk2(float lo, float hi) {
    return f2bf_rne(lo) | (f2bf_rne(hi) << 16);
}
__device__ __forceinline__ float bflo(unsigned u) { return __uint_as_float(u << 16); }
__device__ __forceinline__ float bfhi(unsigned u) { return __uint_as_float(u & 0xffff0000u); }

__global__ void init_out_k(float* __restrict__ out) {
    int i = blockIdx.x * blockDim.x + threadIdx.x;
    float4* o4 = (float4*)out;
    if (i < 2097152) o4[i] = make_float4(-1.f, -1.f, -1.f, -1.f);
}

__global__ void init_k(int* __restrict__ winner, int* __restrict__ widx,
                       int* __restrict__ count) {
    int i = blockIdx.x * blockDim.x + threadIdx.x;
    if (i < HWCELLS) { winner[i] = -1; widx[i] = -1; }
    if (i == 0) *count = 0;
}

__global__ void prep_k(const float* __restrict__ pc, const int* __restrict__ px,
                       const int* __restrict__ py,
                       const float* __restrict__ ng, const float* __restrict__ nb,
                       const float* __restrict__ nm, const float* __restrict__ nv,
                       float* __restrict__ xn8, int* __restrict__ winner) {
    int i = blockIdx.x * blockDim.x + threadIdx.x;
    if (i >= NPTS) return;
    float v[5];
#pragma unroll
    for (int c = 0; c < 5; ++c) {
        float s = ng[c] * rsqrtf(nv[c] + EPSF);
        float t = nb[c] - nm[c] * s;
        v[c] = pc[i * 5 + c] * s + t;
    }
    float4* dst = (float4*)&xn8[(size_t)i * 8];
    dst[0] = make_float4(v[0], v[1], v[2], v[3]);
    dst[1] = make_float4(v[4], 0.f, 0.f, 0.f);
    int cell = py[i] * WW + px[i];
    atomicMax(&winner[cell], i);
}

__global__ void compact_k(const int* __restrict__ winner,
                          const int* __restrict__ px, const int* __restrict__ py,
                          int* __restrict__ ids, int* __restrict__ widx,
                          int* __restrict__ count) {
    int n = blockIdx.x * blockDim.x + threadIdx.x;
    if (n >= NPTS) return;
    int cell = py[n] * WW + px[n];
    if (winner[cell] == n) {
        int slot = atomicAdd(count, 1);
        ids[slot] = n;
        widx[cell] = slot;
    }
}

__global__ void pad_k(int* __restrict__ ids, const int* __restrict__ count) {
    int i = blockIdx.x * blockDim.x + threadIdx.x;
    int c = *count;
    if (i >= c && i < NPTS) ids[i] = ids[0];
}

__global__ void fold_k(const float* __restrict__ w2a,
                       const float* __restrict__ g2a, const float* __restrict__ b2a,
                       const float* __restrict__ m2a, const float* __restrict__ v2a,
                       const float* __restrict__ g2b, const float* __restrict__ b2b,
                       const float* __restrict__ m2b, const float* __restrict__ v2b,
                       const float* __restrict__ w2b,
                       const float* __restrict__ c1w, const float* __restrict__ c1b,
                       const float* __restrict__ fw, const float* __restrict__ fbias,
                       float* __restrict__ w2af8, float* __restrict__ b2o,
                       unsigned short* __restrict__ w2bB,
                       unsigned short* __restrict__ fwallB) {
    int d = threadIdx.x;  // 0..127
    float s2b = g2b[d] * rsqrtf(v2b[d] + EPSF);
    float t2b = b2b[d] - m2b[d] * s2b;
    float acc = 0.f;
#pragma unroll
    for (int c = 0; c < 5; ++c) {
        float s2a = g2a[c] * rsqrtf(v2a[c] + EPSF);
        float t2a = b2a[c] - m2a[c] * s2a;
        float wv = w2a[d * 5 + c];
        w2af8[d * 8 + c] = s2b * wv * s2a;
        acc += s2b * wv * t2a;
    }
    w2af8[d * 8 + 5] = 0.f; w2af8[d * 8 + 6] = 0.f; w2af8[d * 8 + 7] = 0.f;
    b2o[d] = acc + t2b;

    for (int i = 0; i < 128; ++i)
        w2bB[d * 128 + i] = (unsigned short)f2bf_rne(w2b[d * 128 + i]);

    for (int j = 0; j < 128; ++j)
        fwallB[d * 160 + j] = (unsigned short)f2bf_rne(fw[d * 256 + 128 + j]);
    float f1[5] = {0.f, 0.f, 0.f, 0.f, 0.f};
    float fbv = fbias[d];
    for (int dd = 0; dd < 128; ++dd) {
        float f = fw[d * 256 + dd];
        fbv += f * c1b[dd];
#pragma unroll
        for (int c = 0; c < 5; ++c) f1[c] += f * c1w[dd * 5 + c];
    }
#pragma unroll
    for (int c = 0; c < 5; ++c)
        fwallB[d * 160 + 128 + c] = (unsigned short)f2bf_rne(f1[c]);
    fwallB[d * 160 + 133] = (unsigned short)f2bf_rne(fbv);
    for (int j = 134; j < 160; ++j) fwallB[d * 160 + j] = 0;
}

// Y[n][din] bf16 = W2A' @ xn[n]  (no bias)
__global__ void y_k(const float* __restrict__ xn8, const float* __restrict__ w2af8,
                    unsigned short* __restrict__ Y) {
    __shared__ float wS[1024];
    int t = threadIdx.x;
    for (int j = t; j < 1024; j += 256) wS[j] = w2af8[j];
    __syncthreads();
    int n = blockIdx.x * 256 + t;
    const float4 xa = *(const float4*)&xn8[(size_t)n * 8];
    const float x4 = xn8[(size_t)n * 8 + 4];
    unsigned* Yo = (unsigned*)(Y + (size_t)n * 128);
#pragma unroll
    for (int blk = 0; blk < 16; ++blk) {
        unsigned p[4];
#pragma unroll
        for (int q = 0; q < 4; ++q) {
            int d = blk * 8 + q * 2;
            const float* wr = &wS[d * 8];
            float a = wr[0]*xa.x + wr[1]*xa.y + wr[2]*xa.z + wr[3]*xa.w + wr[4]*x4;
            const float* wr2 = &wS[(d + 1) * 8];
            float b = wr2[0]*xa.x + wr2[1]*xa.y + wr2[2]*xa.z + wr2[3]*xa.w + wr2[4]*x4;
            p[q] = pk2(a, b);
        }
        uint4 u; u.x = p[0]; u.y = p[1]; u.z = p[2]; u.w = p[3];
        *(uint4*)&Yo[blk * 4] = u;
    }
}

// fused MFMA main over COMPACTED winner points: 32 pts/block, 256 thr (4 waves)
__launch_bounds__(256, 5)
__global__ void main_k(const int* __restrict__ ids, const int* __restrict__ countp,
                       const int* __restrict__ nbrs,
                       const float* __restrict__ xn8,
                       const int* __restrict__ px, const int* __restrict__ py,
                       const unsigned short* __restrict__ Y,
                       const float* __restrict__ b2,
                       const unsigned short* __restrict__ w2bB,
                       const unsigned short* __restrict__ fwallB,
                       float* __restrict__ featsC, float* __restrict__ outp,
                       int modeA) {
    const int n0 = blockIdx.x * QPTS;
    if (n0 >= *countp) return;

    __shared__ char  lds[16384];   // G double buffer; reused as M after the loop
    __shared__ int   idS[QPTS];
    __shared__ int   nbS[QPTS * 16];
    __shared__ float xnS[QPTS][8];
    __shared__ int   cellS[QPTS];

    const int t = threadIdx.x;
    const int w = t >> 6;
    const int l = t & 63;
    const int l15 = l & 15;
    const int lg  = l >> 4;

    if (t < QPTS) idS[t] = ids[n0 + t];
    __syncthreads();

    for (int j = t; j < QPTS * 16; j += 256) nbS[j] = nbrs[idS[j >> 4] * 16 + (j & 15)];
    if (t < QPTS) {
        int id = idS[t];
        float4 a = *(const float4*)&xn8[(size_t)id * 8];
        float b = xn8[(size_t)id * 8 + 4];
        xnS[t][0] = a.x; xnS[t][1] = a.y; xnS[t][2] = a.z; xnS[t][3] = a.w;
        xnS[t][4] = b;
        cellS[t] = py[id] * WW + px[id];
    }

    // A fragments: w2b rows [w*32, w*32+32), all K=128
    short8 afrag[2][4];
#pragma unroll
    for (int rt = 0; rt < 2; ++rt)
#pragma unroll
        for (int ks = 0; ks < 4; ++ks) {
            int row = w * 32 + rt * 16 + l15;
            int k0 = ks * 32 + lg * 8;
            afrag[rt][ks] = *(const short8*)(w2bB + row * 128 + k0);
        }

    // g-producer role: dins dinblk*4..+3, pts ptblk*4..+3
    const int dinblk = t & 31;
    const int ptblk  = t >> 5;
    const float4 b2q = *(const float4*)&b2[dinblk * 4];
    float c0a[4][4];
#pragma unroll
    for (int i = 0; i < 4; ++i) {
        int id = idS[ptblk * 4 + i];
        uint2 yp = *(const uint2*)(Y + id * 128 + dinblk * 4);
        c0a[i][0] = b2q.x - bflo(yp.x);
        c0a[i][1] = b2q.y - bfhi(yp.x);
        c0a[i][2] = b2q.z - bflo(yp.y);
        c0a[i][3] = b2q.w - bfhi(yp.y);
    }
    __syncthreads();  // nbS ready

    uint2 ycur[4], ynxt[4];
#pragma unroll
    for (int i = 0; i < 4; ++i) {
        int nb = nbS[(ptblk * 4 + i) * 16 + 1];
        ycur[i] = *(const uint2*)(Y + nb * 128 + dinblk * 4);
    }

    const f32x4 zero4 = {0.f, 0.f, 0.f, 0.f};
    f32x4 mmax[2][2];
#pragma unroll
    for (int rt = 0; rt < 2; ++rt)
#pragma unroll
        for (int ct = 0; ct < 2; ++ct)
#pragma unroll
            for (int j = 0; j < 4; ++j) mmax[rt][ct][j] = -1e30f;

    for (int kk = 0; kk < 15; ++kk) {
        if (kk < 14) {
#pragma unroll
            for (int i = 0; i < 4; ++i) {
                int nb = nbS[(ptblk * 4 + i) * 16 + kk + 2];
                ynxt[i] = *(const uint2*)(Y + nb * 128 + dinblk * 4);
            }
        }
        {   // gelu -> G[kk&1]
            char* Gb = lds + (kk & 1) * 8192;
#pragma unroll
            for (int i = 0; i < 4; ++i) {
                int pt = ptblk * 4 + i;
                float g0 = gelu_f(bflo(ycur[i].x) + c0a[i][0]);
                float g1 = gelu_f(bfhi(ycur[i].x) + c0a[i][1]);
                float g2 = gelu_f(bflo(ycur[i].y) + c0a[i][2]);
                float g3 = gelu_f(bfhi(ycur[i].y) + c0a[i][3]);
                uint2 pr; pr.x = pk2(g0, g1); pr.y = pk2(g2, g3);
                *(uint2*)(Gb + pt * 256 + ((dinblk * 8) ^ ((pt & 15) << 4))) = pr;
            }
        }
        __syncthreads();
        {   // MFMA on G[kk&1]
            const char* Gr = lds + (kk & 1) * 8192;
            f32x4 acc[2][2];
#pragma unroll
            for (int ks = 0; ks < 4; ++ks) {
                short8 bfrag[2];
#pragma unroll
                for (int ct = 0; ct < 2; ++ct) {
                    int pt = ct * 16 + l15;
                    int kb = (ks * 32 + lg * 8) * 2;
                    bfrag[ct] = *(const short8*)(Gr + pt * 256 + (kb ^ ((pt & 15) << 4)));
                }
#pragma unroll
                for (int rt = 0; rt < 2; ++rt)
#pragma unroll
                    for (int ct = 0; ct < 2; ++ct)
                        acc[rt][ct] = __builtin_amdgcn_mfma_f32_16x16x32_bf16(
                            afrag[rt][ks], bfrag[ct], ks == 0 ? zero4 : acc[rt][ct], 0, 0, 0);
            }
#pragma unroll
            for (int rt = 0; rt < 2; ++rt)
#pragma unroll
                for (int ct = 0; ct < 2; ++ct)
#pragma unroll
                    for (int j = 0; j < 4; ++j)
                        mmax[rt][ct][j] = fmaxf(mmax[rt][ct][j], acc[rt][ct][j]);
        }
        if (kk < 14) {
#pragma unroll
            for (int i = 0; i < 4; ++i) ycur[i] = ynxt[i];
        }
    }

    __syncthreads();  // all MFMA reads of G done before M overlay

    // running max -> M as B-operand [pt][k=dout] bf16 (k<128 swizzled), + xn tail
    {
        char* Mb = lds;
#pragma unroll
        for (int rt = 0; rt < 2; ++rt)
#pragma unroll
            for (int ct = 0; ct < 2; ++ct) {
                int pt = ct * 16 + l15;
                int dout = w * 32 + rt * 16 + lg * 4;
                unsigned lo = pk2(mmax[rt][ct][0], mmax[rt][ct][1]);
                unsigned hi = pk2(mmax[rt][ct][2], mmax[rt][ct][3]);
                int sw = (pt & 15) << 4;
                *(unsigned*)(Mb + pt * 320 + ((dout * 2) ^ sw)) = lo;
                *(unsigned*)(Mb + pt * 320 + (((dout + 2) * 2) ^ sw)) = hi;
            }
        if (t < QPTS) {
            unsigned v0 = pk2(xnS[t][0], xnS[t][1]);
            unsigned v1 = pk2(xnS[t][2], xnS[t][3]);
            unsigned v2 = pk2(xnS[t][4], 1.0f);
            uint4 a; a.x = v0; a.y = v1; a.z = v2; a.w = 0u;
            uint4 z; z.x = 0u; z.y = 0u; z.z = 0u; z.w = 0u;
            *(uint4*)(Mb + t * 320 + 256) = a;
            *(uint4*)(Mb + t * 320 + 272) = z;
            *(uint4*)(Mb + t * 320 + 288) = z;
            *(uint4*)(Mb + t * 320 + 304) = z;
        }
    }
    __syncthreads();

    // final GEMM: feats[e][pt] = fwallB(128x160) @ M(160xQPTS)
    f32x4 facc[2][2];
    const char* Mr = lds;
#pragma unroll
    for (int ks = 0; ks < 5; ++ks) {
        short8 af[2], bfr[2];
#pragma unroll
        for (int rt = 0; rt < 2; ++rt) {
            int row = w * 32 + rt * 16 + l15;
            af[rt] = *(const short8*)(fwallB + row * 160 + ks * 32 + lg * 8);
        }
#pragma unroll
        for (int ct = 0; ct < 2; ++ct) {
            int pt = ct * 16 + l15;
            int kb = (ks * 32 + lg * 8) * 2;
            int kbs = (kb < 256) ? (kb ^ ((pt & 15) << 4)) : kb;
            bfr[ct] = *(const short8*)(Mr + pt * 320 + kbs);
        }
#pragma unroll
        for (int rt = 0; rt < 2; ++rt)
#pragma unroll
            for (int ct = 0; ct < 2; ++ct)
                facc[rt][ct] = __builtin_amdgcn_mfma_f32_16x16x32_bf16(
                    af[rt], bfr[ct], ks == 0 ? zero4 : facc[rt][ct], 0, 0, 0);
    }

    if (modeA) {
        // coalesced compact write: featsC[slot][e]
#pragma unroll
        for (int ct = 0; ct < 2; ++ct) {
            int slot = n0 + ct * 16 + l15;
#pragma unroll
            for (int rt = 0; rt < 2; ++rt) {
                int e0 = w * 32 + rt * 16 + lg * 4;
                *(f32x4*)&featsC[(size_t)slot * 128 + e0] = facc[rt][ct];
            }
        }
    } else {
#pragma unroll
        for (int ct = 0; ct < 2; ++ct) {
            int cell = cellS[ct * 16 + l15];
#pragma unroll
            for (int rt = 0; rt < 2; ++rt) {
                int e0 = w * 32 + rt * 16 + lg * 4;
#pragma unroll
                for (int j = 0; j < 4; ++j)
                    outp[(size_t)(e0 + j) * HWCELLS + cell] = facc[rt][ct][j];
            }
        }
    }
}

// transpose-scatter: coalesced writes of out[e][cell], gathers featsC rows
__global__ void scatter_k(const int* __restrict__ widx,
                          const float* __restrict__ featsC,
                          float* __restrict__ outp) {
    int cell = blockIdx.x * 256 + threadIdx.x;
    int slot = widx[cell];
    int sl = slot < 0 ? 0 : slot;
    bool inv = slot < 0;
    const float4* src = (const float4*)&featsC[(size_t)sl * 128];
#pragma unroll 8
    for (int e4 = 0; e4 < 32; ++e4) {
        float4 v = src[e4];
        float a = inv ? -1.f : v.x;
        float b = inv ? -1.f : v.y;
        float c = inv ? -1.f : v.z;
        float d = inv ? -1.f : v.w;
        outp[(size_t)(e4 * 4 + 0) * HWCELLS + cell] = a;
        outp[(size_t)(e4 * 4 + 1) * HWCELLS + cell] = b;
        outp[(size_t)(e4 * 4 + 2) * HWCELLS + cell] = c;
        outp[(size_t)(e4 * 4 + 3) * HWCELLS + cell] = d;
    }
}

extern "C" void kernel_launch(void* const* d_in, const int* in_sizes, int n_in,
                              void* d_out, int out_size, void* d_ws, size_t ws_size,
                              hipStream_t stream) {
    const float* pc        = (const float*)d_in[0];
    const int*   neighbors = (const int*)d_in[1];
    const int*   px        = (const int*)d_in[2];
    const int*   py        = (const int*)d_in[3];
    const float* norm_g    = (const float*)d_in[4];
    const float* norm_b    = (const float*)d_in[5];
    const float* norm_m    = (const float*)d_in[6];
    const float* norm_v    = (const float*)d_in[7];
    const float* conv1_w   = (const float*)d_in[8];
    const float* conv1_b   = (const float*)d_in[9];
    const float* bn2a_g    = (const float*)d_in[10];
    const float* bn2a_b    = (const float*)d_in[11];
    const float* bn2a_m    = (const float*)d_in[12];
    const float* bn2a_v    = (const float*)d_in[13];
    const float* w2a       = (const float*)d_in[14];
    const float* bn2b_g    = (const float*)d_in[15];
    const float* bn2b_b    = (const float*)d_in[16];
    const float* bn2b_m    = (const float*)d_in[17];
    const float* bn2b_v    = (const float*)d_in[18];
    const float* w2b       = (const float*)d_in[19];
    const float* final_w   = (const float*)d_in[20];
    const float* final_b   = (const float*)d_in[21];
    float* out = (float*)d_out;

    char* ws = (char*)d_ws;
    float*          xn8    = (float*)(ws);                      // 2,097,152 B
    int*            winner = (int*)(ws + 2097152);              //   262,144 B
    int*            widx   = (int*)(ws + 2359296);              //   262,144 B
    int*            ids    = (int*)(ws + 2621440);              //   262,144 B
    int*            count  = (int*)(ws + 2883584);              //       256 B
    float*          w2af8  = (float*)(ws + 2883840);            //     4,096 B
    float*          b2     = (float*)(ws + 2887936);            //       512 B
    unsigned short* w2bB   = (unsigned short*)(ws + 2888448);   //    32,768 B
    unsigned short* fwallB = (unsigned short*)(ws + 2921216);   //    40,960 B
    unsigned short* Y      = (unsigned short*)(ws + 2962432);   // 16,777,216 B
    float*          featsC = (float*)(ws + 19739648);           // 33,554,432 B (mode A)
    const int modeA = (ws_size >= (size_t)53294080) ? 1 : 0;

    init_k<<<256, 256, 0, stream>>>(winner, widx, count);
    prep_k<<<256, 256, 0, stream>>>(pc, px, py, norm_g, norm_b, norm_m, norm_v, xn8, winner);
    fold_k<<<1, 128, 0, stream>>>(w2a, bn2a_g, bn2a_b, bn2a_m, bn2a_v,
                                  bn2b_g, bn2b_b, bn2b_m, bn2b_v, w2b,
                                  conv1_w, conv1_b, final_w, final_b,
                                  w2af8, b2, w2bB, fwallB);
    y_k<<<256, 256, 0, stream>>>(xn8, w2af8, Y);
    compact_k<<<256, 256, 0, stream>>>(winner, px, py, ids, widx, count);
    pad_k<<<256, 256, 0, stream>>>(ids, count);
    if (!modeA) init_out_k<<<8192, 256, 0, stream>>>(out);
    main_k<<<2048, 256, 0, stream>>>(ids, count, neighbors, xn8, px, py,
                                     Y, b2, w2bB, fwallB,
                                     modeA ? featsC : out, out, modeA);
    if (modeA) scatter_k<<<256, 256, 0, stream>>>(widx, featsC, out);
}